// Round 12
// baseline (1169.078 us; speedup 1.0000x reference)
//
#include <hip/hip_runtime.h>

#define HN 192
#define TT 2048
#define NCLS 12
#define ROWB 768
// LDS layout (bytes): W0p occupies [0, 150528): 196 rows x 768B
//   rows 0..3 = zero pad rows (ff1=-1 lands there); neuron j's column-row at (j+4)*768
#define LDS_S0    150528           // 2 x 768B s0 double buffer (parity)
#define LDS_LIST1 152064           // wave1 list: 1024B data + 256B junk
#define LDS_FEAT  153344           // 768B
#define LDS_TOTAL 154112
// ws float layout: [W0p 196*192][w1 zero row 192][w1 rows (j+1)*192][256 junk]
#define W1OFF 37632                // float offset of w1 zero row

__global__ void snn_pack_k(const float* __restrict__ Wc, float* __restrict__ ws) {
  int id = blockIdx.x * 256 + threadIdx.x;
  if (id < 768) {                                  // W0p pad rows 0..3
    ws[id] = 0.0f;
  } else if (id < 37632) {                         // W0p data: row j at (j+4)*192
    int d = id - 768, j = d / 192, o = d % 192;
    ws[(j + 4) * 192 + o] = Wc[o * 192 + j];       // layer-0 W[o][j]
  } else if (id < 37824) {                         // w1 zero row
    ws[id] = 0.0f;
  } else if (id < 74688) {                         // w1 data: row j at W1OFF+(j+1)*192
    int d = id - 37824, j = d / 192, o = d % 192;
    ws[W1OFF + (j + 1) * 192 + o] = Wc[36864 + o * 192 + j];
  } else if (id < 74944) {                         // junk tail
    ws[id - 74688 + 74880] = 0.0f;
  }
}

__device__ __forceinline__ float4 add4(float4 a, float4 b) {
  return make_float4(a.x + b.x, a.y + b.y, a.z + b.z, a.w + b.w);
}
__device__ __forceinline__ int lanecnt_lt(unsigned long long m) {
  return __builtin_amdgcn_mbcnt_hi((unsigned)(m >> 32),
           __builtin_amdgcn_mbcnt_lo((unsigned)m, 0u));
}
// lowest set bit index, -1 when zero (uniform path -> SALU s_ff1 via isel)
__device__ __forceinline__ int ffs64(unsigned long long m) {
  return __ffsll((long long)m) - 1;
}

#define READC(da, db, base, c) do { \
  da = *(const int4*)((base) + (c) * 32); \
  db = *(const int4*)((base) + (c) * 32 + 16); } while (0)

#define ISS8Q(p, ca, cb, basep) do { \
  p##0 = *(const float4*)((basep) + (unsigned)(ca).x + ln16); \
  p##1 = *(const float4*)((basep) + (unsigned)(ca).y + ln16); \
  p##2 = *(const float4*)((basep) + (unsigned)(ca).z + ln16); \
  p##3 = *(const float4*)((basep) + (unsigned)(ca).w + ln16); \
  p##4 = *(const float4*)((basep) + (unsigned)(cb).x + ln16); \
  p##5 = *(const float4*)((basep) + (unsigned)(cb).y + ln16); \
  p##6 = *(const float4*)((basep) + (unsigned)(cb).z + ln16); \
  p##7 = *(const float4*)((basep) + (unsigned)(cb).w + ln16); } while (0)

#define CONS8Q(acc, p) acc = add4(acc, \
  add4(add4(add4(p##0, p##1), add4(p##2, p##3)), \
       add4(add4(p##4, p##5), add4(p##6, p##7))))

// extract one offset from word-mask m of word w: off = idx*3072 + (w+4)*768
// (idx = -1 on empty -> off = w*768 = zero pad row)
#define EXT1(dst, m, wc) do { dst = ffs64(m) * 3072 + (wc); m &= m - 1; } while (0)

// 2 waves per batch, one-step-lagged pipeline.  Wave0 (layer 0): ballot masks
// stay wave-uniform; spike offsets extracted via ff1 chains (no LDS list), and
// the NEXT step's 16 gather reads are issued BEFORE the barrier so their DS
// latency hides under the barrier + preamble.  Wave1 (layer 1): r10 structure
// (LDS list + global gather with a full iteration of flight).
__global__ __launch_bounds__(128, 1) void snn_main_k(
    const float* __restrict__ x, const float* __restrict__ W_in,
    const float* __restrict__ b_in, const float* __restrict__ b_cells,
    const float* __restrict__ W_head, const float* __restrict__ b_head,
    const float* __restrict__ ws, float* __restrict__ out)
{
  extern __shared__ char lds[];
  const int tid = threadIdx.x;
  const int ln  = tid & 63;
  const bool isW0 = (tid < 64);
  const int b   = blockIdx.x;
  const unsigned ln16 = (unsigned)ln << 4;
  const char* ldsb = lds;
  char* list1b = lds + LDS_LIST1;
  float* feat  = (float*)(lds + LDS_FEAT);
  const char* w1zb = (const char*)ws + W1OFF * 4;   // w1 zero row = offset base

  // stage W0p (incl. its 4 zero pad rows) into LDS
  {
    const float4* src = (const float4*)ws;
    float4* dst = (float4*)lds;
    for (int i = tid; i < W1OFF / 4; i += 128) dst[i] = src[i];
  }
  __syncthreads();

  // opaque zero: forces x loads to VMEM so lgkm counter stays purely DS
  int vz;
  asm volatile("v_mov_b32 %0, 0" : "=v"(vz));

  // per-lane constants (4 neurons/lane both layers; lanes 48-63 parked)
  float wi0[4], wi1[4], wi2[4], zb[4], b1z[4];
  #pragma unroll
  for (int k = 0; k < 4; ++k) {
    int i = 4 * ln + k;
    bool a = (i < HN);
    int ii = a ? i : 0;
    wi0[k] = a ? W_in[ii * 3 + 0] : 0.f;
    wi1[k] = a ? W_in[ii * 3 + 1] : 0.f;
    wi2[k] = a ? W_in[ii * 3 + 2] : 0.f;
    zb[k]  = a ? (b_in[ii] + b_cells[ii]) : -1e30f;
    b1z[k] = a ? b_cells[HN + ii] : -1e30f;
  }
  const float* __restrict__ xb = x + (size_t)b * TT * 3;
  const int vo = ln * 3072;

  // wave0 state: pre-issued gather results + leftover overflow masks
  float v0k[4] = {0, 0, 0, 0};
  unsigned long long lm0 = 0, lm1 = 0, lm2 = 0, lm3 = 0;
  float4 qq0,qq1,qq2,qq3,qq4,qq5,qq6,qq7,qq8,qq9,qq10,qq11,qq12,qq13,qq14,qq15;
  qq0=qq1=qq2=qq3=qq4=qq5=qq6=qq7=make_float4(0.f,0.f,0.f,0.f);
  qq8=qq9=qq10=qq11=qq12=qq13=qq14=qq15=qq0;
  float x0 = xb[vz + 0], x1 = xb[vz + 1], x2 = xb[vz + 2];
  // wave1 state
  float v1k[4] = {0, 0, 0, 0}, cntk[4] = {0, 0, 0, 0};
  int n1 = 0;
  float4 gA0, gA1, gA2, gA3, gA4, gA5, gA6, gA7;
  float4 gB0, gB1, gB2, gB3, gB4, gB5, gB6, gB7;
  if (!isW0) {
    int4 dz = {0, 0, 0, 0};                       // initial pad gather (zero row)
    ISS8Q(gA, dz, dz, w1zb);
    gB0=gB1=gB2=gB3=gB4=gB5=gB6=gB7=make_float4(0.f,0.f,0.f,0.f);
  }

  #pragma unroll 1
  for (int i = 0; i <= TT; ++i) {
    if (isW0) {
      if (i < TT) {
        // ======== wave 0: layer-0 step i ========
        const int wp = i & 1;
        // consume the 16 pre-issued reads (data arrived during barrier)
        float4 a0v = add4(add4(add4(add4(qq0,qq1),add4(qq2,qq3)),
                               add4(add4(qq4,qq5),add4(qq6,qq7))),
                          add4(add4(add4(qq8,qq9),add4(qq10,qq11)),
                               add4(add4(qq12,qq13),add4(qq14,qq15))));
        // rare overflow: leftover spikes beyond 4/word, gathered now
        if (lm0 | lm1 | lm2 | lm3) {
          #pragma unroll 1
          for (int w = 0; w < 4; ++w) {
            unsigned long long m = (w==0)?lm0:(w==1)?lm1:(w==2)?lm2:lm3;
            while (m) {
              int off; EXT1(off, m, (w + 4) * 768);
              a0v = add4(a0v, *(const float4*)(ldsb + (unsigned)off + ln16));
            }
          }
          lm0 = lm1 = lm2 = lm3 = 0;
        }
        // input projection + next-x prefetch (VMEM, in flight)
        float zarr[4];
        #pragma unroll
        for (int k = 0; k < 4; ++k)
          zarr[k] = x0 * wi0[k] + x1 * wi1[k] + x2 * wi2[k] + zb[k];
        const int tn = (i + 1 < TT) ? i + 1 : 0;
        const float nx0 = xb[tn * 3 + vz + 0];
        const float nx1 = xb[tn * 3 + vz + 1];
        const float nx2 = xb[tn * 3 + vz + 2];
        // LIF layer 0 (exact reference op order), flattened
        const float a0arr[4] = {a0v.x, a0v.y, a0v.z, a0v.w};
        float s0f[4];
        unsigned long long M0, M1, M2, M3;
        {
          float u, v;
          u = zarr[0] + a0arr[0]; v = v0k[0] + (u - v0k[0]) * 0.5f;
          bool s = (v >= 1.0f); M0 = __ballot(s ? 1 : 0);
          s0f[0] = s ? 1.0f : 0.0f; v0k[0] = s ? 0.0f : v;
          u = zarr[1] + a0arr[1]; v = v0k[1] + (u - v0k[1]) * 0.5f;
          bool s1 = (v >= 1.0f); M1 = __ballot(s1 ? 1 : 0);
          s0f[1] = s1 ? 1.0f : 0.0f; v0k[1] = s1 ? 0.0f : v;
          u = zarr[2] + a0arr[2]; v = v0k[2] + (u - v0k[2]) * 0.5f;
          bool s2 = (v >= 1.0f); M2 = __ballot(s2 ? 1 : 0);
          s0f[2] = s2 ? 1.0f : 0.0f; v0k[2] = s2 ? 0.0f : v;
          u = zarr[3] + a0arr[3]; v = v0k[3] + (u - v0k[3]) * 0.5f;
          bool s3 = (v >= 1.0f); M3 = __ballot(s3 ? 1 : 0);
          s0f[3] = s3 ? 1.0f : 0.0f; v0k[3] = s3 ? 0.0f : v;
        }
        // publish s0(i)
        if (ln < 48)
          *(float4*)(lds + LDS_S0 + wp * 768 + ln16) =
              make_float4(s0f[0], s0f[1], s0f[2], s0f[3]);
        asm volatile("" ::: "memory");     // writes stay before the reads below
        // uniform ff1 extraction: 4 offsets per word; leftovers carried
        int of0,of1,of2,of3,of4,of5,of6,of7,of8,of9,of10,of11,of12,of13,of14,of15;
        {
          unsigned long long m0 = M0, m1 = M1, m2 = M2, m3 = M3;
          EXT1(of0,  m0, 3072); EXT1(of1,  m0, 3072);
          EXT1(of2,  m0, 3072); EXT1(of3,  m0, 3072);
          EXT1(of4,  m1, 3840); EXT1(of5,  m1, 3840);
          EXT1(of6,  m1, 3840); EXT1(of7,  m1, 3840);
          EXT1(of8,  m2, 4608); EXT1(of9,  m2, 4608);
          EXT1(of10, m2, 4608); EXT1(of11, m2, 4608);
          EXT1(of12, m3, 5376); EXT1(of13, m3, 5376);
          EXT1(of14, m3, 5376); EXT1(of15, m3, 5376);
          lm0 = m0; lm1 = m1; lm2 = m2; lm3 = m3;
        }
        // issue next step's gather now -> flies across the barrier
        qq0  = *(const float4*)(ldsb + (unsigned)of0  + ln16);
        qq1  = *(const float4*)(ldsb + (unsigned)of1  + ln16);
        qq2  = *(const float4*)(ldsb + (unsigned)of2  + ln16);
        qq3  = *(const float4*)(ldsb + (unsigned)of3  + ln16);
        qq4  = *(const float4*)(ldsb + (unsigned)of4  + ln16);
        qq5  = *(const float4*)(ldsb + (unsigned)of5  + ln16);
        qq6  = *(const float4*)(ldsb + (unsigned)of6  + ln16);
        qq7  = *(const float4*)(ldsb + (unsigned)of7  + ln16);
        qq8  = *(const float4*)(ldsb + (unsigned)of8  + ln16);
        qq9  = *(const float4*)(ldsb + (unsigned)of9  + ln16);
        qq10 = *(const float4*)(ldsb + (unsigned)of10 + ln16);
        qq11 = *(const float4*)(ldsb + (unsigned)of11 + ln16);
        qq12 = *(const float4*)(ldsb + (unsigned)of12 + ln16);
        qq13 = *(const float4*)(ldsb + (unsigned)of13 + ln16);
        qq14 = *(const float4*)(ldsb + (unsigned)of14 + ln16);
        qq15 = *(const float4*)(ldsb + (unsigned)of15 + ln16);
        // ensure the s0 write retired (DS retires in order); 16 reads stay out
        asm volatile("s_waitcnt lgkmcnt(15)" ::: "memory");
        x0 = nx0; x1 = nx1; x2 = nx2;
      }
    } else {
      if (i > 0) {
        // ======== wave 1: layer-1 step i-1 (r10 structure) ========
        const int rp = (i - 1) & 1;
        const float4 s0v = *(const float4*)(lds + LDS_S0 + rp * 768 + ln16);
        float4 a1v = make_float4(0.f, 0.f, 0.f, 0.f);
        CONS8Q(a1v, gA);
        if (n1 > 8) CONS8Q(a1v, gB);
        if (n1 > 16) {
          int4 e2a, e2b;
          float4 r0, r1, r2, r3, r4, r5, r6, r7;
          READC(e2a, e2b, list1b, 2);
          ISS8Q(r, e2a, e2b, w1zb);
          CONS8Q(a1v, r);
          if (n1 > 24) {
            READC(e2a, e2b, list1b, 3);
            ISS8Q(r, e2a, e2b, w1zb);
            CONS8Q(a1v, r);
          }
          if (n1 > 32) {
            #pragma unroll 1
            for (int g = 4; g * 8 < n1; ++g) {
              READC(e2a, e2b, list1b, g);
              ISS8Q(r, e2a, e2b, w1zb);
              CONS8Q(a1v, r);
            }
          }
        }
        const float a1arr[4] = {a1v.x + s0v.x, a1v.y + s0v.y,
                                a1v.z + s0v.z, a1v.w + s0v.w};
        float s1w[4];
        bool sq[4];
        unsigned long long nn0, nn1, nn2, nn3;
        {
          float u, v;
          u = b1z[0] + a1arr[0]; v = v1k[0] + (u - v1k[0]) * 0.5f;
          sq[0] = (v >= 1.0f); nn0 = __ballot(sq[0] ? 1 : 0);
          s1w[0] = sq[0] ? 1.0f : 0.0f; v1k[0] = sq[0] ? 0.0f : v;
          u = b1z[1] + a1arr[1]; v = v1k[1] + (u - v1k[1]) * 0.5f;
          sq[1] = (v >= 1.0f); nn1 = __ballot(sq[1] ? 1 : 0);
          s1w[1] = sq[1] ? 1.0f : 0.0f; v1k[1] = sq[1] ? 0.0f : v;
          u = b1z[2] + a1arr[2]; v = v1k[2] + (u - v1k[2]) * 0.5f;
          sq[2] = (v >= 1.0f); nn2 = __ballot(sq[2] ? 1 : 0);
          s1w[2] = sq[2] ? 1.0f : 0.0f; v1k[2] = sq[2] ? 0.0f : v;
          u = b1z[3] + a1arr[3]; v = v1k[3] + (u - v1k[3]) * 0.5f;
          sq[3] = (v >= 1.0f); nn3 = __ballot(sq[3] ? 1 : 0);
          s1w[3] = sq[3] ? 1.0f : 0.0f; v1k[3] = sq[3] ? 0.0f : v;
        }
        cntk[0] += s1w[0]; cntk[1] += s1w[1]; cntk[2] += s1w[2]; cntk[3] += s1w[3];
        const int r0c  = (int)__popcll(nn0);
        const int r01  = r0c + (int)__popcll(nn1);
        const int r012 = r01 + (int)__popcll(nn2);
        const int p1n  = r012 + (int)__popcll(nn3);
        const int jk = 256 + ln;
        {
          int s;
          s = sq[0] ? lanecnt_lt(nn0)          : jk; *(int*)(list1b + 4 * s) = vo + ROWB;
          s = sq[1] ? (r0c  + lanecnt_lt(nn1)) : jk; *(int*)(list1b + 4 * s) = vo + 2 * ROWB;
          s = sq[2] ? (r01  + lanecnt_lt(nn2)) : jk; *(int*)(list1b + 4 * s) = vo + 3 * ROWB;
          s = sq[3] ? (r012 + lanecnt_lt(nn3)) : jk; *(int*)(list1b + 4 * s) = vo + 4 * ROWB;
        }
        *(int*)(list1b + 4 * (p1n + ln)) = 0;        // pads -> zero row
        if (i < TT) {
          int4 d0a, d0b, d1a, d1b;
          asm volatile("" ::: "memory");
          READC(d0a, d0b, list1b, 0);
          READC(d1a, d1b, list1b, 1);
          ISS8Q(gA, d0a, d0b, w1zb);                 // flies across next step
          if (p1n > 8) ISS8Q(gB, d1a, d1b, w1zb);
        }
        n1 = p1n;
      }
    }
    asm volatile("" ::: "memory");
    __builtin_amdgcn_s_barrier();
    __builtin_amdgcn_sched_barrier(0);
    asm volatile("" ::: "memory");
  }

  __syncthreads();
  // epilogue: exact mean (count * 2^-11) + head GEMV
  if (!isW0 && ln < 48) {
    const float r = 1.0f / 2048.0f;
    ((float4*)feat)[ln] = make_float4(cntk[0] * r, cntk[1] * r, cntk[2] * r, cntk[3] * r);
  }
  __syncthreads();
  if (tid < NCLS) {
    float a = b_head[tid];
    const float* wh = W_head + tid * HN;
    #pragma unroll 8
    for (int q = 0; q < HN; ++q) a += feat[q] * wh[q];
    out[b * NCLS + tid] = a;
  }
}

extern "C" void kernel_launch(void* const* d_in, const int* in_sizes, int n_in,
                              void* d_out, int out_size, void* d_ws, size_t ws_size,
                              hipStream_t stream) {
  const float* x       = (const float*)d_in[0];
  const float* W_in    = (const float*)d_in[1];
  const float* b_in    = (const float*)d_in[2];
  const float* W_cells = (const float*)d_in[3];
  const float* b_cells = (const float*)d_in[4];
  const float* W_head  = (const float*)d_in[5];
  const float* b_head  = (const float*)d_in[6];
  float* out = (float*)d_out;
  float* ws  = (float*)d_ws;   // 300544 bytes used

  snn_pack_k<<<(74944 + 255) / 256, 256, 0, stream>>>(W_cells, ws);
  snn_main_k<<<128, 128, LDS_TOTAL, stream>>>(
      x, W_in, b_in, b_cells, W_head, b_head, ws, out);
}